// Round 1
// baseline (641.889 us; speedup 1.0000x reference)
//
#include <hip/hip_runtime.h>
#include <math.h>

#define D_ 64
#define R_ 256
#define T_ 4096
#define H_ 16
#define BH_ 64
#define EPS_ 1e-6f
#define SCALE_ 0.0625f   // 1/sqrt(256)

// ============================================================
// Stage 1: per (split-chunk, head): compute k' tiles, accumulate
// kv_part[r][d] and ksum_part[r].  grid(split, BH), 256 threads.
// ============================================================
__global__ __launch_bounds__(256)
void k_stage1(const float* __restrict__ kg, const float* __restrict__ vg,
              const float* __restrict__ mg, const float* __restrict__ Wg,
              float* __restrict__ kv_part, float* __restrict__ ks_part,
              int split)
{
    __shared__ float Wl[D_][R_];       // 64 KB  [d][r]
    __shared__ float kp[64][R_];       // 64 KB  [t][r]  (k' tile)
    __shared__ float sc[64 * 72];      // 18 KB  kT[d][t] stride 72, then v[t][d] stride 64
    __shared__ float xn_l[64], sl_l[64], mv_l[64];

    const int tid = threadIdx.x;
    const int s  = blockIdx.x;
    const int bh = blockIdx.y;
    const int b  = bh >> 4;            // H_ = 16
    const int TC = T_ / split;

    // stage W once per block
    for (int i = tid; i < D_ * R_ / 4; i += 256)
        ((float4*)Wl)[i] = ((const float4*)Wg)[i];

    const int tg8  = tid & 7;          // proj t-group  -> t0 = 8*tg8
    const int rg32 = tid >> 3;         // proj+acc r-group -> r0 = 8*rg32
    const int dg8  = tid & 7;          // acc d-group  -> d0 = 8*dg8
    const int t0p = tg8 * 8, r0 = rg32 * 8, d0 = dg8 * 8;

    float acc[8][8];
    float ksa[8];
#pragma unroll
    for (int i = 0; i < 8; ++i) {
        ksa[i] = 0.f;
#pragma unroll
        for (int j = 0; j < 8; ++j) acc[i][j] = 0.f;
    }

    const int nch = TC >> 6;           // chunks of 64 rows
    for (int c = 0; c < nch; ++c) {
        const int tseq = s * TC + c * 64;
        const long rowb = (long)bh * T_ + tseq;

        __syncthreads();               // previous chunk fully consumed
        if (tid < 64) {
            float m = mg[b * T_ + tseq + tid];
            mv_l[tid] = m;
            sl_l[tid] = m * SCALE_;
        }
        __syncthreads();

        // k tile transpose-load: kT[d][t] = sc[d*72 + t]
#pragma unroll
        for (int p = 0; p < 4; ++p) {
            int idx = p * 256 + tid;
            int t = idx >> 4;
            int d4 = (idx & 15) << 2;
            float4 kk = *(const float4*)&kg[(rowb + t) * D_ + d4];
            sc[(d4 + 0) * 72 + t] = kk.x;
            sc[(d4 + 1) * 72 + t] = kk.y;
            sc[(d4 + 2) * 72 + t] = kk.z;
            sc[(d4 + 3) * 72 + t] = kk.w;
        }
        __syncthreads();

        // row norms
        if (tid < 64) {
            float s2 = 0.f;
#pragma unroll
            for (int d = 0; d < D_; ++d) { float x = sc[d * 72 + tid]; s2 = fmaf(x, x, s2); }
            xn_l[tid] = 0.5f * s2;
        }
        __syncthreads();

        // projection: pr[8t][8r]
        float pr[8][8];
#pragma unroll
        for (int i = 0; i < 8; ++i)
#pragma unroll
            for (int j = 0; j < 8; ++j) pr[i][j] = 0.f;

        for (int d = 0; d < D_; ++d) {
            float a[8], w[8];
            *(float4*)&a[0] = *(const float4*)&sc[d * 72 + t0p];
            *(float4*)&a[4] = *(const float4*)&sc[d * 72 + t0p + 4];
            *(float4*)&w[0] = *(const float4*)&Wl[d][r0];
            *(float4*)&w[4] = *(const float4*)&Wl[d][r0 + 4];
#pragma unroll
            for (int i = 0; i < 8; ++i)
#pragma unroll
                for (int j = 0; j < 8; ++j) pr[i][j] = fmaf(a[i], w[j], pr[i][j]);
        }

        // exp + masked scale, store k' tile
#pragma unroll
        for (int i = 0; i < 8; ++i) {
            int t = t0p + i;
            float xn = xn_l[t], sl = sl_l[t];
            float e[8];
#pragma unroll
            for (int j = 0; j < 8; ++j) e[j] = expf(pr[i][j] - xn) * sl;
            *(float4*)&kp[t][r0]     = *(float4*)&e[0];
            *(float4*)&kp[t][r0 + 4] = *(float4*)&e[4];
        }
        __syncthreads();               // all kT reads done, kp visible

        // v tile (scaled by mask) overwrites sc: v[t][d] = sc[t*64+d]
#pragma unroll
        for (int p = 0; p < 4; ++p) {
            int idx = p * 256 + tid;
            int t = idx >> 4;
            int d4 = (idx & 15) << 2;
            float4 vv = *(const float4*)&vg[(rowb + t) * D_ + d4];
            float m = mv_l[t];
            vv.x *= m; vv.y *= m; vv.z *= m; vv.w *= m;
            *(float4*)&sc[t * 64 + d4] = vv;
        }
        __syncthreads();

        // accumulate kv += k'^T v  and ksum
        for (int t = 0; t < 64; ++t) {
            float a[8], bb[8];
            *(float4*)&a[0]  = *(const float4*)&kp[t][r0];
            *(float4*)&a[4]  = *(const float4*)&kp[t][r0 + 4];
            *(float4*)&bb[0] = *(const float4*)&sc[t * 64 + d0];
            *(float4*)&bb[4] = *(const float4*)&sc[t * 64 + d0 + 4];
#pragma unroll
            for (int i = 0; i < 8; ++i)
#pragma unroll
                for (int j = 0; j < 8; ++j) acc[i][j] = fmaf(a[i], bb[j], acc[i][j]);
            if (dg8 == 0) {
#pragma unroll
                for (int i = 0; i < 8; ++i) ksa[i] += a[i];
            }
        }
    }

    // write partials
    const long pb = (long)(s * BH_ + bh) * (R_ * D_);
#pragma unroll
    for (int i = 0; i < 8; ++i) {
        float4 o0, o1;
        o0.x = acc[i][0]; o0.y = acc[i][1]; o0.z = acc[i][2]; o0.w = acc[i][3];
        o1.x = acc[i][4]; o1.y = acc[i][5]; o1.z = acc[i][6]; o1.w = acc[i][7];
        *(float4*)&kv_part[pb + (long)(r0 + i) * D_ + d0]     = o0;
        *(float4*)&kv_part[pb + (long)(r0 + i) * D_ + d0 + 4] = o1;
    }
    if (dg8 == 0) {
        const long sb = (long)(s * BH_ + bh) * R_;
#pragma unroll
        for (int i = 0; i < 8; ++i) ks_part[sb + r0 + i] = ksa[i];
    }
}

// ============================================================
// Reduce partials: kv_final, ksum_final
// ============================================================
__global__ __launch_bounds__(256)
void k_reduce(const float* __restrict__ kvp, const float* __restrict__ ksp,
              float* __restrict__ kvf, float* __restrict__ ksf, int split)
{
    const long NKV = (long)BH_ * R_ * D_;
    const long NKS = (long)BH_ * R_;
    long i = (long)blockIdx.x * 256 + threadIdx.x;
    if (i < NKV) {
        float s = 0.f;
        for (int p = 0; p < split; ++p) s += kvp[(long)p * NKV + i];
        kvf[i] = s;
    } else if (i < NKV + NKS) {
        long j = i - NKV;
        float s = 0.f;
        for (int p = 0; p < split; ++p) s += ksp[(long)p * NKS + j];
        ksf[j] = s;
    }
}

// ============================================================
// Stage 2: per (256-row q tile, head): q' on the fly (r-strips of 64),
// out = q' kv, z = q' ksum, out /= (z+eps).  grid(T/256, BH), 256 thr.
// ============================================================
__global__ __launch_bounds__(256)
void k_stage2(const float* __restrict__ qg, const float* __restrict__ Wg,
              const float* __restrict__ kvf, const float* __restrict__ ksf,
              float* __restrict__ outg)
{
    __shared__ float qT[D_ * 256];     // 64 KB  [d][t] stride 256
    __shared__ float qpT[64 * 260];    // 65 KB  [rr][t] stride 260 (q' strip, transposed)
    __shared__ float buf[64 * 68];     // 17 KB  W-strip [d][rr] / kv-strip [rr][d], stride 68
    __shared__ float xn_l[256];
    __shared__ float ks_l[R_];

    const int tid = threadIdx.x;
    const int tq0 = blockIdx.x * 256;
    const int bh  = blockIdx.y;
    const long rowb = (long)bh * T_ + tq0;

    // q transpose-load
#pragma unroll
    for (int p = 0; p < 16; ++p) {
        int idx = p * 256 + tid;
        int t = idx >> 4;
        int d4 = (idx & 15) << 2;
        float4 qq = *(const float4*)&qg[(rowb + t) * D_ + d4];
        qT[(d4 + 0) * 256 + t] = qq.x;
        qT[(d4 + 1) * 256 + t] = qq.y;
        qT[(d4 + 2) * 256 + t] = qq.z;
        qT[(d4 + 3) * 256 + t] = qq.w;
    }
    ks_l[tid] = ksf[bh * R_ + tid];
    __syncthreads();

    // row norms (one t per thread)
    {
        float s2 = 0.f;
#pragma unroll
        for (int d = 0; d < D_; ++d) { float x = qT[d * 256 + tid]; s2 = fmaf(x, x, s2); }
        xn_l[tid] = 0.5f * s2;
    }
    __syncthreads();

    const int tg32 = tid >> 3;         // t0 = 8*tg32 (proj & acc)
    const int g8   = tid & 7;          // rr0 (proj) / d0 (acc) = 8*g8
    const int t0 = tg32 * 8, rr0 = g8 * 8, d0 = g8 * 8;

    float oacc[8][8];
    float zacc[8];
#pragma unroll
    for (int i = 0; i < 8; ++i) {
        zacc[i] = 0.f;
#pragma unroll
        for (int j = 0; j < 8; ++j) oacc[i][j] = 0.f;
    }

    for (int rs = 0; rs < 4; ++rs) {
        const int rbase = rs * 64;
        __syncthreads();               // prior strip's buf/qpT reads done

        // load W strip -> buf[d*68 + rr]
#pragma unroll
        for (int p = 0; p < 4; ++p) {
            int idx = p * 256 + tid;
            int d = idx >> 4;
            int rr4 = (idx & 15) << 2;
            *(float4*)&buf[d * 68 + rr4] = *(const float4*)&Wg[d * R_ + rbase + rr4];
        }
        __syncthreads();

        // projection strip: pr[8t][8rr]
        float pr[8][8];
#pragma unroll
        for (int i = 0; i < 8; ++i)
#pragma unroll
            for (int j = 0; j < 8; ++j) pr[i][j] = 0.f;

        for (int d = 0; d < D_; ++d) {
            float a[8], w[8];
            *(float4*)&a[0] = *(const float4*)&qT[d * 256 + t0];
            *(float4*)&a[4] = *(const float4*)&qT[d * 256 + t0 + 4];
            *(float4*)&w[0] = *(const float4*)&buf[d * 68 + rr0];
            *(float4*)&w[4] = *(const float4*)&buf[d * 68 + rr0 + 4];
#pragma unroll
            for (int i = 0; i < 8; ++i)
#pragma unroll
                for (int j = 0; j < 8; ++j) pr[i][j] = fmaf(a[i], w[j], pr[i][j]);
        }

        // exp + transposed store into qpT[rr][t]
#pragma unroll
        for (int j = 0; j < 8; ++j) {
            int rr = rr0 + j;
            float e[8];
#pragma unroll
            for (int i = 0; i < 8; ++i) e[i] = expf(pr[i][j] - xn_l[t0 + i]) * SCALE_;
            *(float4*)&qpT[rr * 260 + t0]     = *(float4*)&e[0];
            *(float4*)&qpT[rr * 260 + t0 + 4] = *(float4*)&e[4];
        }
        __syncthreads();               // all W reads done, qpT visible

        // load kv strip -> buf[rr*68 + d]
#pragma unroll
        for (int p = 0; p < 4; ++p) {
            int idx = p * 256 + tid;
            int rr = idx >> 4;
            int d4 = (idx & 15) << 2;
            *(float4*)&buf[rr * 68 + d4] =
                *(const float4*)&kvf[((long)bh * R_ + rbase + rr) * D_ + d4];
        }
        __syncthreads();

        // accumulate out and z over this strip
        for (int r = 0; r < 64; ++r) {
            float a[8], bb[8];
            *(float4*)&a[0]  = *(const float4*)&qpT[r * 260 + t0];
            *(float4*)&a[4]  = *(const float4*)&qpT[r * 260 + t0 + 4];
            *(float4*)&bb[0] = *(const float4*)&buf[r * 68 + d0];
            *(float4*)&bb[4] = *(const float4*)&buf[r * 68 + d0 + 4];
            float ks = ks_l[rbase + r];
#pragma unroll
            for (int i = 0; i < 8; ++i) {
                zacc[i] = fmaf(a[i], ks, zacc[i]);
#pragma unroll
                for (int j = 0; j < 8; ++j) oacc[i][j] = fmaf(a[i], bb[j], oacc[i][j]);
            }
        }
    }

    // epilogue: divide by z+eps, store
#pragma unroll
    for (int i = 0; i < 8; ++i) {
        float zi = 1.f / (zacc[i] + EPS_);
        float4 o0, o1;
        o0.x = oacc[i][0] * zi; o0.y = oacc[i][1] * zi;
        o0.z = oacc[i][2] * zi; o0.w = oacc[i][3] * zi;
        o1.x = oacc[i][4] * zi; o1.y = oacc[i][5] * zi;
        o1.z = oacc[i][6] * zi; o1.w = oacc[i][7] * zi;
        *(float4*)&outg[(rowb + t0 + i) * D_ + d0]     = o0;
        *(float4*)&outg[(rowb + t0 + i) * D_ + d0 + 4] = o1;
    }
}

// ============================================================
extern "C" void kernel_launch(void* const* d_in, const int* in_sizes, int n_in,
                              void* d_out, int out_size, void* d_ws, size_t ws_size,
                              hipStream_t stream)
{
    const float* q    = (const float*)d_in[0];
    const float* k    = (const float*)d_in[1];
    const float* v    = (const float*)d_in[2];
    const float* mask = (const float*)d_in[3];
    const float* W    = (const float*)d_in[4];
    float* out = (float*)d_out;

    const long NKV = (long)BH_ * R_ * D_;   // 1,048,576
    const long NKS = (long)BH_ * R_;        // 16,384

    int split = 8;
    while (split > 1) {
        size_t need = sizeof(float) * (size_t)((NKV + NKS) * (long)(split + 1));
        if (need <= ws_size) break;
        split >>= 1;
    }

    float* wsf = (float*)d_ws;
    float* kvf = wsf;
    float* ksf = kvf + NKV;
    float* kvp = ksf + NKS;
    float* ksp = kvp + (long)split * NKV;

    k_stage1<<<dim3(split, BH_), 256, 0, stream>>>(k, v, mask, W, kvp, ksp, split);

    long nred = NKV + NKS;
    k_reduce<<<dim3((unsigned)((nred + 255) / 256)), 256, 0, stream>>>(kvp, ksp, kvf, ksf, split);

    k_stage2<<<dim3(T_ / 256, BH_), 256, 0, stream>>>(q, W, kvf, ksf, out);
}

// Round 2
// 274.632 us; speedup vs baseline: 2.3373x; 2.3373x over previous
//
#include <hip/hip_runtime.h>
#include <math.h>

#define T_     4096
#define BH_    64
#define EPS_   1e-6f
#define SCALE_ 0.0625f   // 1/sqrt(256)

typedef _Float16 h16;
typedef __attribute__((ext_vector_type(4))) _Float16 h16x4;
typedef __attribute__((ext_vector_type(8))) _Float16 h16x8;
typedef __attribute__((ext_vector_type(4))) short    short4v;
typedef __attribute__((ext_vector_type(8))) short    bf16x8;
typedef __attribute__((ext_vector_type(4))) float    f32x4;

__device__ __forceinline__ short f2bf(float x) {
    unsigned u = __float_as_uint(x);
    u += 0x7fffu + ((u >> 16) & 1u);           // RNE to bf16
    return (short)(u >> 16);
}
__device__ __forceinline__ float bf2f(short h) {
    return __uint_as_float(((unsigned)(unsigned short)h) << 16);
}

// ============================================================
// prep: W (64x256) -> W^T padded f16 hi/lo planes [256][72]
// ============================================================
__global__ __launch_bounds__(256)
void k_prep(const float* __restrict__ Wg, h16* __restrict__ wtp)
{
    int d = blockIdx.x;      // 0..63
    int r = threadIdx.x;     // 0..255
    float x = Wg[d * 256 + r];
    h16 hi = (h16)x;
    h16 lo = (h16)(x - (float)hi);
    wtp[r * 72 + d]            = hi;
    wtp[256 * 72 + r * 72 + d] = lo;
}

// ============================================================
// Stage 1: per (t-chunk s, head bh): proj_k (f16x3 MFMA) -> exp
// -> kv accumulate (bf16x3 MFMA). 8 waves: (tg 0..1) x (rg 0..3).
// wave tile: proj 64t x 64r ; kv 64r x 64d over its 64-t strip.
// ============================================================
__global__ __launch_bounds__(512, 2)
void k_stage1(const float* __restrict__ kg, const float* __restrict__ vg,
              const float* __restrict__ mg, const h16* __restrict__ wtp,
              float* __restrict__ kv_part, float* __restrict__ ks_part, int nch)
{
    __shared__ __align__(16) h16   Wt[2 * 256 * 72];   // 73728 B  (hi plane, lo plane)
    __shared__ __align__(16) short vTh[64 * 136];      // 17408 B  v^T hi (bf16)
    __shared__ __align__(16) short vTl[64 * 136];      // 17408 B  v^T lo
    __shared__ float norm_l[128];
    __shared__ float msk_l[128];
    __shared__ float np[4][128];
    __shared__ __align__(16) float red[128 * 68];      // 34816 B
    __shared__ float ksb[2][256];

    const int tid  = threadIdx.x;
    const int lane = tid & 63, l15 = lane & 15, q = lane >> 4;
    const int wid  = tid >> 6;
    const int rg = wid & 3, tg = wid >> 2;
    const int s = blockIdx.x, bh = blockIdx.y, b = bh >> 4;
    const long rowb = (long)bh * T_;

    {   // stage W^T hi/lo (ws layout identical to LDS layout)
        const float4* src = (const float4*)wtp;
        float4* dst = (float4*)Wt;
#pragma unroll
        for (int i = 0; i < 9; ++i) dst[i * 512 + tid] = src[i * 512 + tid];
    }

    f32x4 kva[4][4];
#pragma unroll
    for (int a = 0; a < 4; ++a)
#pragma unroll
        for (int c2 = 0; c2 < 4; ++c2) { f32x4 z4 = {0.f, 0.f, 0.f, 0.f}; kva[a][c2] = z4; }
    float ksa[4] = {0.f, 0.f, 0.f, 0.f};

    for (int c = 0; c < nch; ++c) {
        const int t0 = (s * nch + c) * 128;
        __syncthreads();   // prev-subtile vT/norm readers done; Wt staged (c==0)

        // ---- stage v^T (mask-scaled, bf16 hi/lo) + k row-norm partials ----
        {
            const int tlv = tid & 127, dq = tid >> 7;
            const float mval = mg[b * T_ + t0 + tlv];
            const float* vrow = vg + (rowb + t0 + tlv) * 64 + dq * 16;
            const float* krow = kg + (rowb + t0 + tlv) * 64 + dq * 16;
            float s2 = 0.f;
#pragma unroll
            for (int j = 0; j < 4; ++j) {
                float4 vv = *(const float4*)(vrow + j * 4);
                float4 kk = *(const float4*)(krow + j * 4);
                s2 += kk.x * kk.x + kk.y * kk.y + kk.z * kk.z + kk.w * kk.w;
                float xs[4] = {vv.x * mval, vv.y * mval, vv.z * mval, vv.w * mval};
#pragma unroll
                for (int e = 0; e < 4; ++e) {
                    int d = dq * 16 + j * 4 + e;
                    short hi = f2bf(xs[e]);
                    short lo = f2bf(xs[e] - bf2f(hi));
                    vTh[d * 136 + tlv] = hi;
                    vTl[d * 136 + tlv] = lo;
                }
            }
            np[dq][tlv] = s2;
        }
        __syncthreads();
        if (tid < 128) {
            norm_l[tid] = 0.5f * (np[0][tid] + np[1][tid] + np[2][tid] + np[3][tid]);
            msk_l[tid]  = mg[b * T_ + t0 + tid] * SCALE_;
        }
        __syncthreads();

        // ---- proj: pr[m][n], rows t = t0+tg*64+m*16+{l15 | 4q+j}, cols r = rg*64+n*16+l15 ----
        f32x4 pr[4][4];
#pragma unroll
        for (int m = 0; m < 4; ++m)
#pragma unroll
            for (int n = 0; n < 4; ++n) { f32x4 z4 = {0.f, 0.f, 0.f, 0.f}; pr[m][n] = z4; }

#pragma unroll
        for (int w = 0; w < 2; ++w) {   // 32-d K windows
            h16x8 ah[4], al[4];
#pragma unroll
            for (int m = 0; m < 4; ++m) {
                const float* arow = kg + (rowb + t0 + tg * 64 + m * 16 + l15) * 64 + w * 32 + q * 4;
                float4 x0 = *(const float4*)arow;
                float4 x1 = *(const float4*)(arow + 16);
                h16x8 hv, lv;
                hv[0] = (h16)x0.x; hv[1] = (h16)x0.y; hv[2] = (h16)x0.z; hv[3] = (h16)x0.w;
                hv[4] = (h16)x1.x; hv[5] = (h16)x1.y; hv[6] = (h16)x1.z; hv[7] = (h16)x1.w;
                lv[0] = (h16)(x0.x - (float)hv[0]); lv[1] = (h16)(x0.y - (float)hv[1]);
                lv[2] = (h16)(x0.z - (float)hv[2]); lv[3] = (h16)(x0.w - (float)hv[3]);
                lv[4] = (h16)(x1.x - (float)hv[4]); lv[5] = (h16)(x1.y - (float)hv[5]);
                lv[6] = (h16)(x1.z - (float)hv[6]); lv[7] = (h16)(x1.w - (float)hv[7]);
                ah[m] = hv; al[m] = lv;
            }
            h16x8 wbh[4], wbl[4];
#pragma unroll
            for (int n = 0; n < 4; ++n) {
                int r = rg * 64 + n * 16 + l15;
                const h16* p  = Wt + r * 72 + w * 32 + q * 4;
                const h16* pl = p + 256 * 72;
                h16x4 a0 = *(const h16x4*)p,  a1 = *(const h16x4*)(p + 16);
                h16x4 b0 = *(const h16x4*)pl, b1 = *(const h16x4*)(pl + 16);
                h16x8 hv, lv;
                hv[0]=a0.x; hv[1]=a0.y; hv[2]=a0.z; hv[3]=a0.w; hv[4]=a1.x; hv[5]=a1.y; hv[6]=a1.z; hv[7]=a1.w;
                lv[0]=b0.x; lv[1]=b0.y; lv[2]=b0.z; lv[3]=b0.w; lv[4]=b1.x; lv[5]=b1.y; lv[6]=b1.z; lv[7]=b1.w;
                wbh[n] = hv; wbl[n] = lv;
            }
#pragma unroll
            for (int m = 0; m < 4; ++m)
#pragma unroll
                for (int n = 0; n < 4; ++n) {
                    pr[m][n] = __builtin_amdgcn_mfma_f32_16x16x32_f16(ah[m], wbh[n], pr[m][n], 0, 0, 0);
                    pr[m][n] = __builtin_amdgcn_mfma_f32_16x16x32_f16(ah[m], wbl[n], pr[m][n], 0, 0, 0);
                    pr[m][n] = __builtin_amdgcn_mfma_f32_16x16x32_f16(al[m], wbh[n], pr[m][n], 0, 0, 0);
                }
        }

        // ---- per 32-t window: exp -> bf16 split A-frags -> kv MFMA ----
#pragma unroll
        for (int W = 0; W < 2; ++W) {
            bf16x8 afh[4], afl[4];
#pragma unroll
            for (int n = 0; n < 4; ++n) {
#pragma unroll
                for (int half = 0; half < 2; ++half) {
                    int m = 2 * W + half;
                    int tl = tg * 64 + m * 16 + q * 4;
#pragma unroll
                    for (int j = 0; j < 4; ++j) {
                        float e = __expf(pr[m][n][j] - norm_l[tl + j]) * msk_l[tl + j];
                        ksa[n] += e;
                        short hi = f2bf(e);
                        short lo = f2bf(e - bf2f(hi));
                        afh[n][half * 4 + j] = hi;
                        afl[n][half * 4 + j] = lo;
                    }
                }
            }
            bf16x8 bvh[4], bvl[4];
#pragma unroll
            for (int nd = 0; nd < 4; ++nd) {
                int d  = nd * 16 + l15;
                int tb = tg * 64 + W * 32 + q * 4;
                short4v a0 = *(const short4v*)(vTh + d * 136 + tb);
                short4v a1 = *(const short4v*)(vTh + d * 136 + tb + 16);
                short4v b0 = *(const short4v*)(vTl + d * 136 + tb);
                short4v b1 = *(const short4v*)(vTl + d * 136 + tb + 16);
                bf16x8 hv, lv;
                hv[0]=a0.x; hv[1]=a0.y; hv[2]=a0.z; hv[3]=a0.w; hv[4]=a1.x; hv[5]=a1.y; hv[6]=a1.z; hv[7]=a1.w;
                lv[0]=b0.x; lv[1]=b0.y; lv[2]=b0.z; lv[3]=b0.w; lv[4]=b1.x; lv[5]=b1.y; lv[6]=b1.z; lv[7]=b1.w;
                bvh[nd] = hv; bvl[nd] = lv;
            }
#pragma unroll
            for (int n = 0; n < 4; ++n)
#pragma unroll
                for (int nd = 0; nd < 4; ++nd) {
                    kva[n][nd] = __builtin_amdgcn_mfma_f32_16x16x32_bf16(afh[n], bvh[nd], kva[n][nd], 0, 0, 0);
                    kva[n][nd] = __builtin_amdgcn_mfma_f32_16x16x32_bf16(afh[n], bvl[nd], kva[n][nd], 0, 0, 0);
                    kva[n][nd] = __builtin_amdgcn_mfma_f32_16x16x32_bf16(afl[n], bvh[nd], kva[n][nd], 0, 0, 0);
                }
        }
    }

    // ---- block-end: reduce kv over tg, write partials ----
    __syncthreads();
#pragma unroll
    for (int n = 0; n < 4; ++n) {      // ksum: sum over q (t-quadrants), write per tg
        float v = ksa[n];
        v += __shfl_xor(v, 16);
        v += __shfl_xor(v, 32);
        if (q == 0) ksb[tg][rg * 64 + n * 16 + l15] = v;
    }
    if (tg == 0) {
#pragma unroll
        for (int n = 0; n < 4; ++n)
#pragma unroll
            for (int nd = 0; nd < 4; ++nd)
#pragma unroll
                for (int j = 0; j < 4; ++j)
                    red[(rg * 64 + n * 16 + q * 4 + j) * 68 + nd * 16 + l15] = kva[n][nd][j];
    }
    __syncthreads();
    if (tg == 1) {
#pragma unroll
        for (int n = 0; n < 4; ++n)
#pragma unroll
            for (int nd = 0; nd < 4; ++nd)
#pragma unroll
                for (int j = 0; j < 4; ++j)
                    red[(rg * 64 + n * 16 + q * 4 + j) * 68 + nd * 16 + l15] += kva[n][nd][j];
    }
    __syncthreads();
    {
        float* dst = kv_part + (long)(s * BH_ + bh) * (256 * 64);
#pragma unroll
        for (int i = 0; i < 8; ++i) {
            int flat = i * 2048 + tid * 4;
            int r = flat >> 6, d = flat & 63;
            *(float4*)(dst + flat) = *(const float4*)(red + r * 68 + d);
        }
        if (tid < 256) ks_part[(long)(s * BH_ + bh) * 256 + tid] = ksb[0][tid] + ksb[1][tid];
    }
}

// ============================================================
// Reduce: sum split partials; emit kv^T as padded bf16 hi/lo
// [bh][plane][64 d][264 r] and ksum_f.  grid(64), 256 thr.
// ============================================================
__global__ __launch_bounds__(256)
void k_reduce(const float* __restrict__ kvp, const float* __restrict__ ksp,
              short* __restrict__ kvt, float* __restrict__ ksf, int split)
{
    __shared__ __align__(16) float red2[256 * 68];
    const int tid = threadIdx.x, bh = blockIdx.x;

    for (int i = 0; i < 16; ++i) {
        int idx4 = i * 256 + tid;
        float4 a = ((const float4*)kvp)[(long)bh * 4096 + idx4];
        for (int p = 1; p < split; ++p) {
            float4 t = ((const float4*)kvp)[((long)p * BH_ + bh) * 4096 + idx4];
            a.x += t.x; a.y += t.y; a.z += t.z; a.w += t.w;
        }
        int flat = idx4 * 4;
        int r = flat >> 6, d = flat & 63;
        *(float4*)(red2 + r * 68 + d) = a;
    }
    {
        float ss = 0.f;
        for (int p = 0; p < split; ++p) ss += ksp[((long)p * BH_ + bh) * 256 + tid];
        ksf[bh * 256 + tid] = ss;
    }
    __syncthreads();
    short* dh = kvt + (long)bh * 33792;
    short* dl = dh + 16896;
    for (int d = 0; d < 64; ++d) {          // tid = r (coalesced writes)
        float x = red2[tid * 68 + d];
        short hi = f2bf(x);
        short lo = f2bf(x - bf2f(hi));
        dh[d * 264 + tid] = hi;
        dl[d * 264 + tid] = lo;
    }
}

// ============================================================
// Stage 2: per (t-tile 128, head): proj^T = W^T q^T (f16x3) -> exp
// (+z via ksum) -> out = q' kv (bf16x3) -> reduce over r-strips ->
// divide by z+eps.  8 waves: (tt 0..1) x (rs 0..3).
// ============================================================
__global__ __launch_bounds__(512, 2)
void k_stage2(const float* __restrict__ qg, const h16* __restrict__ wtp,
              const short* __restrict__ kvt, const float* __restrict__ ksf,
              float* __restrict__ outg)
{
    __shared__ __align__(16) char smem[73728 + 67584 + 1024 + 2048];  // 144384 B
    h16*   Wt     = (h16*)smem;                       // [2][256*72]
    short* kvTh   = (short*)(smem + 73728);           // [64*264] bf16 hi
    short* kvTl   = kvTh + 64 * 264;                  // lo
    float* ksum_l = (float*)(smem + 73728 + 67584);   // [256]
    float* zb     = ksum_l + 256;                     // [4][128]
    float* red    = (float*)smem;                     // alias Wt (dead after proj)

    const int tid  = threadIdx.x;
    const int lane = tid & 63, l15 = lane & 15, q = lane >> 4;
    const int wid  = tid >> 6;
    const int rs = wid & 3, tt = wid >> 2;
    const int bh = blockIdx.y, t0 = blockIdx.x * 128;
    const long rowb = (long)bh * T_;

    {
        const float4* src = (const float4*)wtp;
        float4* dst = (float4*)Wt;
#pragma unroll
        for (int i = 0; i < 9; ++i) dst[i * 512 + tid] = src[i * 512 + tid];
        const float4* s2 = (const float4*)(kvt + (long)bh * 33792);
        float4* d2 = (float4*)kvTh;
#pragma unroll
        for (int i = 0; i < 9; ++i) { int idx = i * 512 + tid; if (idx < 4224) d2[idx] = s2[idx]; }
        if (tid < 256) ksum_l[tid] = ksf[bh * 256 + tid];
    }
    __syncthreads();

    // ---- proj^T: rows r = rs*64+m*16+{l15|4q+j}, cols t = t0+tt*64+n*16+l15 ----
    f32x4 pr[4][4];
#pragma unroll
    for (int m = 0; m < 4; ++m)
#pragma unroll
        for (int n = 0; n < 4; ++n) { f32x4 z4 = {0.f, 0.f, 0.f, 0.f}; pr[m][n] = z4; }
    float nacc[4] = {0.f, 0.f, 0.f, 0.f};

#pragma unroll
    for (int w = 0; w < 2; ++w) {
        h16x8 aWh[4], aWl[4];
#pragma unroll
        for (int m = 0; m < 4; ++m) {
            int r = rs * 64 + m * 16 + l15;
            const h16* p  = Wt + r * 72 + w * 32 + q * 4;
            const h16* pl = p + 256 * 72;
            h16x4 a0 = *(const h16x4*)p,  a1 = *(const h16x4*)(p + 16);
            h16x4 b0 = *(const h16x4*)pl, b1 = *(const h16x4*)(pl + 16);
            h16x8 hv, lv;
            hv[0]=a0.x; hv[1]=a0.y; hv[2]=a0.z; hv[3]=a0.w; hv[4]=a1.x; hv[5]=a1.y; hv[6]=a1.z; hv[7]=a1.w;
            lv[0]=b0.x; lv[1]=b0.y; lv[2]=b0.z; lv[3]=b0.w; lv[4]=b1.x; lv[5]=b1.y; lv[6]=b1.z; lv[7]=b1.w;
            aWh[m] = hv; aWl[m] = lv;
        }
        h16x8 qbh[4], qbl[4];
#pragma unroll
        for (int n = 0; n < 4; ++n) {
            const float* qrow = qg + (rowb + t0 + tt * 64 + n * 16 + l15) * 64 + w * 32 + q * 4;
            float4 x0 = *(const float4*)qrow;
            float4 x1 = *(const float4*)(qrow + 16);
            nacc[n] += x0.x * x0.x + x0.y * x0.y + x0.z * x0.z + x0.w * x0.w
                     + x1.x * x1.x + x1.y * x1.y + x1.z * x1.z + x1.w * x1.w;
            h16x8 hv, lv;
            hv[0] = (h16)x0.x; hv[1] = (h16)x0.y; hv[2] = (h16)x0.z; hv[3] = (h16)x0.w;
            hv[4] = (h16)x1.x; hv[5] = (h16)x1.y; hv[6] = (h16)x1.z; hv[7] = (h16)x1.w;
            lv[0] = (h16)(x0.x - (float)hv[0]); lv[1] = (h16)(x0.y - (float)hv[1]);
            lv[2] = (h16)(x0.z - (float)hv[2]); lv[3] = (h16)(x0.w - (float)hv[3]);
            lv[4] = (h16)(x1.x - (float)hv[4]); lv[5] = (h16)(x1.y - (float)hv[5]);
            lv[6] = (h16)(x1.z - (float)hv[6]); lv[7] = (h16)(x1.w - (float)hv[7]);
            qbh[n] = hv; qbl[n] = lv;
        }
#pragma unroll
        for (int m = 0; m < 4; ++m)
#pragma unroll
            for (int n = 0; n < 4; ++n) {
                pr[m][n] = __builtin_amdgcn_mfma_f32_16x16x32_f16(aWh[m], qbh[n], pr[m][n], 0, 0, 0);
                pr[m][n] = __builtin_amdgcn_mfma_f32_16x16x32_f16(aWh[m], qbl[n], pr[m][n], 0, 0, 0);
                pr[m][n] = __builtin_amdgcn_mfma_f32_16x16x32_f16(aWl[m], qbh[n], pr[m][n], 0, 0, 0);
            }
    }
    float normt[4];
#pragma unroll
    for (int n = 0; n < 4; ++n) {
        float v = nacc[n];
        v += __shfl_xor(v, 16);
        v += __shfl_xor(v, 32);
        normt[n] = 0.5f * v;
    }

    // ---- exp + z + out-GEMM per 32-r window ----
    f32x4 oac[4][4];
#pragma unroll
    for (int n = 0; n < 4; ++n)
#pragma unroll
        for (int nd = 0; nd < 4; ++nd) { f32x4 z4 = {0.f, 0.f, 0.f, 0.f}; oac[n][nd] = z4; }
    float zp[4] = {0.f, 0.f, 0.f, 0.f};

#pragma unroll
    for (int W = 0; W < 2; ++W) {
        bf16x8 aph[4], apl[4];
#pragma unroll
        for (int n = 0; n < 4; ++n) {
#pragma unroll
            for (int half = 0; half < 2; ++half) {
                int m = 2 * W + half;
                int rl = rs * 64 + m * 16 + q * 4;
#pragma unroll
                for (int j = 0; j < 4; ++j) {
                    float e = __expf(pr[m][n][j] - normt[n]) * SCALE_;
                    zp[n] += e * ksum_l[rl + j];
                    short hi = f2bf(e);
                    short lo = f2bf(e - bf2f(hi));
                    aph[n][half * 4 + j] = hi;
                    apl[n][half * 4 + j] = lo;
                }
            }
        }
        bf16x8 bkh[4], bkl[4];
#pragma unroll
        for (int nd = 0; nd < 4; ++nd) {
            int d  = nd * 16 + l15;
            int rb = rs * 64 + W * 32 + q * 4;
            short4v a0 = *(const short4v*)(kvTh + d * 264 + rb);
            short4v a1 = *(const short4v*)(kvTh + d * 264 + rb + 16);
            short4v b0 = *(const short4v*)(kvTl + d * 264 + rb);
            short4v b1 = *(const short4v*)(kvTl + d * 264 + rb + 16);
            bf16x8 hv, lv;
            hv[0]=a0.x; hv[1]=a0.y; hv[2]=a0.z; hv[3]=a0.w; hv[4]=a1.x; hv[5]=a1.y; hv[6]=a1.z; hv[7]=a1.w;
            lv[0]=b0.x; lv[1]=b0.y; lv[2]=b0.z; lv[3]=b0.w; lv[4]=b1.x; lv[5]=b1.y; lv[6]=b1.z; lv[7]=b1.w;
            bkh[nd] = hv; bkl[nd] = lv;
        }
#pragma unroll
        for (int n = 0; n < 4; ++n)
#pragma unroll
            for (int nd = 0; nd < 4; ++nd) {
                oac[n][nd] = __builtin_amdgcn_mfma_f32_16x16x32_bf16(aph[n], bkh[nd], oac[n][nd], 0, 0, 0);
                oac[n][nd] = __builtin_amdgcn_mfma_f32_16x16x32_bf16(aph[n], bkl[nd], oac[n][nd], 0, 0, 0);
                oac[n][nd] = __builtin_amdgcn_mfma_f32_16x16x32_bf16(apl[n], bkh[nd], oac[n][nd], 0, 0, 0);
            }
    }
#pragma unroll
    for (int n = 0; n < 4; ++n) {   // z partials (sum over r-quadrants)
        float v = zp[n];
        v += __shfl_xor(v, 16);
        v += __shfl_xor(v, 32);
        if (q == 0) zb[rs * 128 + tt * 64 + n * 16 + l15] = v;
    }
    __syncthreads();   // all proj reads of Wt done -> red (alias) writable; zb visible

    // ---- sequential reduce over r-strips into red ----
#pragma unroll
    for (int p = 0; p < 4; ++p) {
        if (rs == p) {
#pragma unroll
            for (int n = 0; n < 4; ++n)
#pragma unroll
                for (int nd = 0; nd < 4; ++nd)
#pragma unroll
                    for (int j = 0; j < 4; ++j) {
                        int idx = (tt * 64 + n * 16 + q * 4 + j) * 68 + nd * 16 + l15;
                        if (p == 0) red[idx] = oac[n][nd][j];
                        else        red[idx] += oac[n][nd][j];
                    }
        }
        __syncthreads();
    }

    // ---- epilogue: divide by z+eps, store ----
#pragma unroll
    for (int i = 0; i < 4; ++i) {
        int flat = i * 2048 + tid * 4;
        int tl = flat >> 6, d = flat & 63;
        float z = zb[0 * 128 + tl] + zb[1 * 128 + tl] + zb[2 * 128 + tl] + zb[3 * 128 + tl] + EPS_;
        float rz = 1.f / z;
        float4 o = *(const float4*)(red + tl * 68 + d);
        o.x *= rz; o.y *= rz; o.z *= rz; o.w *= rz;
        *(float4*)(outg + (rowb + t0 + tl) * 64 + d) = o;
    }
}

// ============================================================
extern "C" void kernel_launch(void* const* d_in, const int* in_sizes, int n_in,
                              void* d_out, int out_size, void* d_ws, size_t ws_size,
                              hipStream_t stream)
{
    const float* q  = (const float*)d_in[0];
    const float* k  = (const float*)d_in[1];
    const float* v  = (const float*)d_in[2];
    const float* m  = (const float*)d_in[3];
    const float* W  = (const float*)d_in[4];
    float* out = (float*)d_out;

    char* ws = (char*)d_ws;
    h16*   wtp = (h16*)ws;                                   // 73728 B
    short* kvt = (short*)(ws + 73728);                       // 64*33792*2 = 4325376 B
    float* ksf = (float*)(ws + 73728 + 4325376);             // 65536 B

    int split = 8;
    while (split > 1) {
        size_t need = 73728ull + 4325376ull + 65536ull
                    + (size_t)split * (4194304ull + 65536ull);
        if (need <= ws_size) break;
        split >>= 1;
    }
    float* kvp = (float*)(ws + 73728 + 4325376 + 65536);
    float* ksp = kvp + (size_t)split * (256 * 64 * BH_);
    int nch = (T_ / split) / 128;

    k_prep  <<<dim3(64),           dim3(256), 0, stream>>>(W, wtp);
    k_stage1<<<dim3(split, BH_),   dim3(512), 0, stream>>>(k, v, m, wtp, kvp, ksp, nch);
    k_reduce<<<dim3(BH_),          dim3(256), 0, stream>>>(kvp, ksp, kvt, ksf, split);
    k_stage2<<<dim3(T_ / 128, BH_), dim3(512), 0, stream>>>(q, wtp, kvt, ksf, out);
}